// Round 1
// baseline (2473.363 us; speedup 1.0000x reference)
//
#include <hip/hip_runtime.h>
#include <stdint.h>

#define N_ROWS 4096
#define DIM    512
#define VOCAB  50000
#define TOPK   10

#define BM 128
#define BN 128
#define BK 16
#define TM 8
#define TN 8

// ---------- w2[v] = ||w_v||^2 : one wave per word ----------
__global__ __launch_bounds__(64) void w2_kernel(const float* __restrict__ W,
                                                float* __restrict__ w2) {
    int v = blockIdx.x;
    if (v >= VOCAB) return;
    const float4* w4 = (const float4*)(W + (size_t)v * DIM);
    int lane = threadIdx.x;
    float4 a = w4[lane];
    float4 b = w4[lane + 64];
    float s = a.x*a.x + a.y*a.y + a.z*a.z + a.w*a.w
            + b.x*b.x + b.y*b.y + b.z*b.z + b.w*b.w;
    #pragma unroll
    for (int off = 32; off > 0; off >>= 1) s += __shfl_down(s, off, 64);
    if (lane == 0) w2[v] = s;
}

// ---------- st[n] = ||w_t||^2 - 2 x_n . w_t : one wave per row ----------
__global__ __launch_bounds__(64) void st_kernel(const float* __restrict__ X,
                                                const float* __restrict__ W,
                                                const int* __restrict__ target,
                                                float* __restrict__ st) {
    int n = blockIdx.x;
    int t = target[n];
    const float4* x4 = (const float4*)(X + (size_t)n * DIM);
    const float4* w4 = (const float4*)(W + (size_t)t * DIM);
    int lane = threadIdx.x;
    float4 xa = x4[lane], xb = x4[lane + 64];
    float4 wa = w4[lane], wb = w4[lane + 64];
    float sxw = xa.x*wa.x + xa.y*wa.y + xa.z*wa.z + xa.w*wa.w
              + xb.x*wb.x + xb.y*wb.y + xb.z*wb.z + xb.w*wb.w;
    float sww = wa.x*wa.x + wa.y*wa.y + wa.z*wa.z + wa.w*wa.w
              + wb.x*wb.x + wb.y*wb.y + wb.z*wb.z + wb.w*wb.w;
    #pragma unroll
    for (int off = 32; off > 0; off >>= 1) {
        sxw += __shfl_down(sxw, off, 64);
        sww += __shfl_down(sww, off, 64);
    }
    if (lane == 0) st[n] = sww - 2.0f * sxw;
}

// ---------- fused GEMM + rank-count ----------
// count[n] += #{v in this block's column tile : v != t_n, s_v ranked before s_t}
__global__ __launch_bounds__(256) void count_kernel(
        const float* __restrict__ X, const float* __restrict__ W,
        const float* __restrict__ w2, const float* __restrict__ st,
        const int* __restrict__ target, int* __restrict__ count) {

    __shared__ float Xs[BK][BM];
    __shared__ float Ws[BK][BN];
    __shared__ float st_s[BM];
    __shared__ int   t_s[BM];
    __shared__ float w2_s[BN];

    const int tid  = threadIdx.x;
    const int row0 = blockIdx.y * BM;
    const int col0 = blockIdx.x * BN;

    if (tid < 128) {
        st_s[tid] = st[row0 + tid];
        t_s[tid]  = target[row0 + tid];
    } else {
        int c = tid - 128;
        int v = col0 + c;
        if (v >= VOCAB) v = VOCAB - 1;
        w2_s[c] = w2[v];
    }

    float acc[TM][TN] = {};
    const int tx = tid & 15;
    const int ty = tid >> 4;

    for (int k0 = 0; k0 < DIM; k0 += BK) {
        // stage 128x16 of X (transposed) and 128x16 of W (transposed)
        #pragma unroll
        for (int j = 0; j < 2; j++) {
            int idx = tid + 256 * j;      // 0..511
            int r   = idx >> 2;           // 0..127
            int kq  = idx & 3;            // 0..3 -> k sub-quad
            float4 xv = *(const float4*)(X + (size_t)(row0 + r) * DIM + k0 + kq * 4);
            Xs[kq*4+0][r] = xv.x; Xs[kq*4+1][r] = xv.y;
            Xs[kq*4+2][r] = xv.z; Xs[kq*4+3][r] = xv.w;
            int v = col0 + r;
            if (v >= VOCAB) v = VOCAB - 1;   // clamp: data unused (predicated at count)
            float4 wv = *(const float4*)(W + (size_t)v * DIM + k0 + kq * 4);
            Ws[kq*4+0][r] = wv.x; Ws[kq*4+1][r] = wv.y;
            Ws[kq*4+2][r] = wv.z; Ws[kq*4+3][r] = wv.w;
        }
        __syncthreads();

        #pragma unroll
        for (int kk = 0; kk < BK; kk++) {
            float a[TM], b[TN];
            #pragma unroll
            for (int i = 0; i < TM; i++) a[i] = Xs[kk][ty * TM + i];
            #pragma unroll
            for (int j = 0; j < TN; j++) b[j] = Ws[kk][tx * TN + j];
            #pragma unroll
            for (int i = 0; i < TM; i++)
                #pragma unroll
                for (int j = 0; j < TN; j++)
                    acc[i][j] += a[i] * b[j];
        }
        __syncthreads();
    }

    // epilogue: predicate + per-thread row counts
    int cnt[TM];
    #pragma unroll
    for (int i = 0; i < TM; i++) {
        cnt[i] = 0;
        float stv = st_s[ty * TM + i];
        int   t   = t_s[ty * TM + i];
        #pragma unroll
        for (int j = 0; j < TN; j++) {
            int v = col0 + tx * TN + j;
            float s = w2_s[tx * TN + j] - 2.0f * acc[i][j];
            // stable top_k: v ranked before t iff s < s_t, or tie with lower index
            if (v < VOCAB && v != t && (s < stv || (s == stv && v < t))) cnt[i]++;
        }
    }
    __syncthreads();

    // reduce 16 column-groups per row via LDS (reuse Xs: 2048 ints fit in 8KB)
    int* scnt = (int*)Xs;
    #pragma unroll
    for (int i = 0; i < TM; i++) scnt[(ty * TM + i) * 16 + tx] = cnt[i];
    __syncthreads();
    if (tid < BM) {
        int s = 0;
        #pragma unroll
        for (int j = 0; j < 16; j++) s += scnt[tid * 16 + j];
        atomicAdd(&count[row0 + tid], s);
    }
}

// ---------- final reduction ----------
__global__ __launch_bounds__(256) void finalize_kernel(const int* __restrict__ count,
                                                       const int* __restrict__ mask,
                                                       float* __restrict__ out) {
    int tid = threadIdx.x;
    int hits = 0, msum = 0;
    for (int n = tid; n < N_ROWS; n += 256) {
        int m = mask[n];
        msum += m;
        if (m && count[n] < TOPK) hits++;
    }
    #pragma unroll
    for (int off = 32; off > 0; off >>= 1) {
        hits += __shfl_down(hits, off, 64);
        msum += __shfl_down(msum, off, 64);
    }
    __shared__ int sh[8];
    int wid = tid >> 6, lane = tid & 63;
    if (lane == 0) { sh[wid] = hits; sh[4 + wid] = msum; }
    __syncthreads();
    if (tid == 0) {
        int H = sh[0] + sh[1] + sh[2] + sh[3];
        int M = sh[4] + sh[5] + sh[6] + sh[7];
        out[0] = (float)H / (float)M;
    }
}

extern "C" void kernel_launch(void* const* d_in, const int* in_sizes, int n_in,
                              void* d_out, int out_size, void* d_ws, size_t ws_size,
                              hipStream_t stream) {
    const float* X      = (const float*)d_in[0];   // logits [4096,512]
    const int*   target = (const int*)d_in[1];     // [4096]
    const int*   mask   = (const int*)d_in[2];     // [4096]
    const float* W      = (const float*)d_in[3];   // word_vectors [50000,512]
    float* out = (float*)d_out;

    // workspace layout (all 16B-aligned): w2 | st | count
    char* ws = (char*)d_ws;
    float* w2    = (float*)ws;                       // 50000 f -> 200704 B padded
    float* st    = (float*)(ws + 200704);            // 4096 f  -> 16384 B
    int*   countp = (int*)(ws + 200704 + 16384);     // 4096 i  -> 16384 B

    hipMemsetAsync(countp, 0, N_ROWS * sizeof(int), stream);
    w2_kernel<<<VOCAB, 64, 0, stream>>>(W, w2);
    st_kernel<<<N_ROWS, 64, 0, stream>>>(X, W, target, st);
    dim3 grid((VOCAB + BN - 1) / BN, N_ROWS / BM);
    count_kernel<<<grid, 256, 0, stream>>>(X, W, w2, st, target, countp);
    finalize_kernel<<<1, 256, 0, stream>>>(countp, mask, out);
}

// Round 2
// 856.216 us; speedup vs baseline: 2.8887x; 2.8887x over previous
//
#include <hip/hip_runtime.h>
#include <stdint.h>

#define N_ROWS 4096
#define DIM    512
#define VOCAB  50000
#define VPAD   50048
#define TOPK   10
#define MARGIN 2.0f

typedef short bf16x8 __attribute__((ext_vector_type(8)));
typedef float f32x4  __attribute__((ext_vector_type(4)));

#define GLOBAL_AS __attribute__((address_space(1)))
#define LDS_AS    __attribute__((address_space(3)))

__device__ __forceinline__ unsigned short f2bf(float f) {
    unsigned int u = __float_as_uint(f);
    u += 0x7fff + ((u >> 16) & 1);          // round-to-nearest-even
    return (unsigned short)(u >> 16);
}

// ---------------- fp32 -> bf16 conversion ----------------
__global__ __launch_bounds__(256) void convert_x(const float* __restrict__ X,
                                                 unsigned short* __restrict__ Xb) {
    int idx = blockIdx.x * 256 + threadIdx.x;            // 4 elems per thread
    float4 f = ((const float4*)X)[idx];
    ((ushort4*)Xb)[idx] = make_ushort4(f2bf(f.x), f2bf(f.y), f2bf(f.z), f2bf(f.w));
}

// one block (128 thr) per word row: convert + w2 (fp32 exact). Pad rows: zeros, w2=1e30.
__global__ __launch_bounds__(128) void convert_w(const float* __restrict__ W,
                                                 unsigned short* __restrict__ Wb,
                                                 float* __restrict__ w2) {
    int v = blockIdx.x, tid = threadIdx.x;
    __shared__ float sh[2];
    if (v < VOCAB) {
        float4 f = ((const float4*)(W + (size_t)v * DIM))[tid];
        ((ushort4*)(Wb + (size_t)v * DIM))[tid] =
            make_ushort4(f2bf(f.x), f2bf(f.y), f2bf(f.z), f2bf(f.w));
        float s = f.x*f.x + f.y*f.y + f.z*f.z + f.w*f.w;
        #pragma unroll
        for (int off = 32; off > 0; off >>= 1) s += __shfl_down(s, off, 64);
        if ((tid & 63) == 0) sh[tid >> 6] = s;
        __syncthreads();
        if (tid == 0) w2[v] = sh[0] + sh[1];
    } else {
        ((ushort4*)(Wb + (size_t)v * DIM))[tid] = make_ushort4(0, 0, 0, 0);
        if (tid == 0) w2[v] = 1e30f;
    }
}

// ---------- st[n] = ||w_t||^2 - 2 x_n . w_t (fp32 exact) ----------
__global__ __launch_bounds__(64) void st_kernel(const float* __restrict__ X,
                                                const float* __restrict__ W,
                                                const int* __restrict__ target,
                                                float* __restrict__ st) {
    int n = blockIdx.x;
    int t = target[n];
    const float4* x4 = (const float4*)(X + (size_t)n * DIM);
    const float4* w4 = (const float4*)(W + (size_t)t * DIM);
    int lane = threadIdx.x;
    float4 xa = x4[lane], xb = x4[lane + 64];
    float4 wa = w4[lane], wb = w4[lane + 64];
    float sxw = xa.x*wa.x + xa.y*wa.y + xa.z*wa.z + xa.w*wa.w
              + xb.x*wb.x + xb.y*wb.y + xb.z*wb.z + xb.w*wb.w;
    float sww = wa.x*wa.x + wa.y*wa.y + wa.z*wa.z + wa.w*wa.w
              + wb.x*wb.x + wb.y*wb.y + wb.z*wb.z + wb.w*wb.w;
    #pragma unroll
    for (int off = 32; off > 0; off >>= 1) {
        sxw += __shfl_down(sxw, off, 64);
        sww += __shfl_down(sww, off, 64);
    }
    if (lane == 0) st[n] = sww - 2.0f * sxw;
}

// ---------------- bf16 MFMA GEMM + band-count ----------------
// 128x128 tile, BK=32, 4 waves (2x2), mfma_f32_16x16x32_bf16, 4x4 frags/wave.
__global__ __launch_bounds__(256) void count_mfma(
        const unsigned short* __restrict__ Xb, const unsigned short* __restrict__ Wb,
        const float* __restrict__ w2, const float* __restrict__ st,
        const int* __restrict__ target,
        int* __restrict__ cnt_def, int* __restrict__ cnt_unc) {

    __shared__ unsigned short Als[128 * 32];
    __shared__ unsigned short Bls[128 * 32];
    __shared__ float w2_s[128];
    __shared__ float st_s[128];
    __shared__ int   t_s[128];
    __shared__ int   pk_s[128];

    const int tid  = threadIdx.x;
    const int wave = tid >> 6, lane = tid & 63;
    const int row0 = blockIdx.x * 128;          // x fastest -> W-tile reuse across 32 blocks
    const int col0 = blockIdx.y * 128;

    if (tid < 128) { w2_s[tid] = w2[col0 + tid]; pk_s[tid] = 0; }
    else           { st_s[tid - 128] = st[row0 + tid - 128];
                     t_s[tid - 128]  = target[row0 + tid - 128]; }

    // staging: each wave stages 32 rows of A and of B; lane -> (row, 16B chunk)
    const unsigned short* ga = Xb + (size_t)(row0 + wave*32 + (lane >> 2)) * DIM + (lane & 3) * 8;
    const unsigned short* gb = Wb + (size_t)(col0 + wave*32 + (lane >> 2)) * DIM + (lane & 3) * 8;
    unsigned short* la0 = &Als[(wave*32     ) * 32];
    unsigned short* la1 = &Als[(wave*32 + 16) * 32];
    unsigned short* lb0 = &Bls[(wave*32     ) * 32];
    unsigned short* lb1 = &Bls[(wave*32 + 16) * 32];

    const int q = lane >> 4, c = lane & 15;     // quad, col-in-16
    const int wm = wave >> 1, wn = wave & 1;
    const unsigned short* ap = &Als[(wm*64 + c) * 32 + q * 8];
    const unsigned short* bp = &Bls[(wn*64 + c) * 32 + q * 8];

    f32x4 acc[4][4];
    #pragma unroll
    for (int i = 0; i < 4; i++)
        #pragma unroll
        for (int j = 0; j < 4; j++) acc[i][j] = (f32x4){0.f, 0.f, 0.f, 0.f};

    for (int k0 = 0; k0 < DIM; k0 += 32) {
        __builtin_amdgcn_global_load_lds((const GLOBAL_AS void*)(ga + k0),           (LDS_AS void*)la0, 16, 0, 0);
        __builtin_amdgcn_global_load_lds((const GLOBAL_AS void*)(ga + 16*DIM + k0),  (LDS_AS void*)la1, 16, 0, 0);
        __builtin_amdgcn_global_load_lds((const GLOBAL_AS void*)(gb + k0),           (LDS_AS void*)lb0, 16, 0, 0);
        __builtin_amdgcn_global_load_lds((const GLOBAL_AS void*)(gb + 16*DIM + k0),  (LDS_AS void*)lb1, 16, 0, 0);
        __syncthreads();
        bf16x8 af[4], bfr[4];
        #pragma unroll
        for (int i = 0; i < 4; i++) af[i]  = *(const bf16x8*)(ap + i * 16 * 32);
        #pragma unroll
        for (int j = 0; j < 4; j++) bfr[j] = *(const bf16x8*)(bp + j * 16 * 32);
        #pragma unroll
        for (int i = 0; i < 4; i++)
            #pragma unroll
            for (int j = 0; j < 4; j++)
                acc[i][j] = __builtin_amdgcn_mfma_f32_16x16x32_bf16(af[i], bfr[j], acc[i][j], 0, 0, 0);
        __syncthreads();
    }

    // epilogue: banded compare-count, no C write. C/D: col=lane&15, row=q*4+reg.
    #pragma unroll
    for (int i = 0; i < 4; i++) {
        #pragma unroll
        for (int reg = 0; reg < 4; reg++) {
            int r = wm*64 + i*16 + q*4 + reg;
            float stv = st_s[r];
            int   t   = t_s[r];
            int def = 0, unc = 0;
            #pragma unroll
            for (int j = 0; j < 4; j++) {
                int col_l = wn*64 + j*16 + c;
                float s = w2_s[col_l] - 2.0f * acc[i][j][reg];
                int v = col0 + col_l;                 // pad cols: w2=1e30 -> never counted
                if (v != t) {
                    if      (s < stv - MARGIN) def++;
                    else if (s < stv + MARGIN) unc++;
                }
            }
            int pk = (def << 16) | unc;               // per-block <=128 each: fits
            pk += __shfl_xor(pk, 1, 64);
            pk += __shfl_xor(pk, 2, 64);
            pk += __shfl_xor(pk, 4, 64);
            pk += __shfl_xor(pk, 8, 64);
            if (c == 0) atomicAdd(&pk_s[r], pk);
        }
    }
    __syncthreads();
    if (tid < 128) {
        int pk = pk_s[tid];
        if (pk) {
            atomicAdd(&cnt_def[row0 + tid], pk >> 16);
            atomicAdd(&cnt_unc[row0 + tid], pk & 0xffff);
        }
    }
}

// ---------------- resolve: definite rows -> hit, ambiguous -> list ----------------
__global__ __launch_bounds__(256) void resolve_kernel(const int* __restrict__ cnt_def,
                                                      const int* __restrict__ cnt_unc,
                                                      int* __restrict__ hit,
                                                      int* __restrict__ amb_rows,
                                                      int* __restrict__ amb_count) {
    int n = blockIdx.x * 256 + threadIdx.x;
    if (n >= N_ROWS) return;
    int d = cnt_def[n], u = cnt_unc[n];
    int h;
    if (d >= TOPK) h = 0;
    else if (d + u < TOPK) h = 1;
    else { int idx = atomicAdd(amb_count, 1); amb_rows[idx] = n; h = 2; }
    hit[n] = h;
}

// ---------------- exact fp32 recount for ambiguous rows (8 chunks/row) ----------------
__global__ __launch_bounds__(256) void exact_kernel(const float* __restrict__ X,
                                                    const float* __restrict__ W,
                                                    const float* __restrict__ w2,
                                                    const float* __restrict__ st,
                                                    const int* __restrict__ target,
                                                    const int* __restrict__ amb_rows,
                                                    const int* __restrict__ amb_count,
                                                    int* __restrict__ count_exact) {
    __shared__ float xs[DIM];
    int tid = threadIdx.x;
    int nw = amb_count[0] * 8;
    for (int w = blockIdx.x; w < nw; w += gridDim.x) {
        int row = amb_rows[w >> 3];
        int chunk = w & 7;
        for (int i = tid; i < DIM; i += 256) xs[i] = X[(size_t)row * DIM + i];
        __syncthreads();
        float stv = st[row];
        int t = target[row];
        int cnt = 0;
        int vend = (chunk + 1) * 6256; if (vend > VOCAB) vend = VOCAB;
        for (int v = chunk * 6256 + tid; v < vend; v += 256) {
            if (v == t) continue;
            const float4* wr = (const float4*)(W + (size_t)v * DIM);
            float dot = 0.f;
            #pragma unroll 8
            for (int k = 0; k < DIM / 4; k++) {
                float4 wv = wr[k];
                dot += xs[4*k]*wv.x + xs[4*k+1]*wv.y + xs[4*k+2]*wv.z + xs[4*k+3]*wv.w;
            }
            float s = w2[v] - 2.f * dot;
            if (s < stv || (s == stv && v < t)) cnt++;
        }
        atomicAdd(&count_exact[row], cnt);
        __syncthreads();
    }
}

// ---------------- final reduction ----------------
__global__ __launch_bounds__(256) void finalize2(const int* __restrict__ hit,
                                                 const int* __restrict__ count_exact,
                                                 const int* __restrict__ mask,
                                                 float* __restrict__ out) {
    int tid = threadIdx.x;
    int hits = 0, msum = 0;
    for (int n = tid; n < N_ROWS; n += 256) {
        int m = mask[n];
        msum += m;
        int h = hit[n];
        int hv = (h == 2) ? (count_exact[n] < TOPK ? 1 : 0) : h;
        if (m) hits += hv;
    }
    #pragma unroll
    for (int off = 32; off > 0; off >>= 1) {
        hits += __shfl_down(hits, off, 64);
        msum += __shfl_down(msum, off, 64);
    }
    __shared__ int sh[8];
    int wid = tid >> 6, lane = tid & 63;
    if (lane == 0) { sh[wid] = hits; sh[4 + wid] = msum; }
    __syncthreads();
    if (tid == 0) {
        int H = sh[0] + sh[1] + sh[2] + sh[3];
        int M = sh[4] + sh[5] + sh[6] + sh[7];
        out[0] = (float)H / (float)M;
    }
}

// ================= round-1 verified fp32 fallback (if ws too small) =================
#define BM 128
#define BN 128
#define BK 16
#define TM 8
#define TN 8

__global__ __launch_bounds__(64) void w2_kernel_fb(const float* __restrict__ W,
                                                   float* __restrict__ w2) {
    int v = blockIdx.x;
    const float4* w4 = (const float4*)(W + (size_t)v * DIM);
    int lane = threadIdx.x;
    float4 a = w4[lane];
    float4 b = w4[lane + 64];
    float s = a.x*a.x + a.y*a.y + a.z*a.z + a.w*a.w
            + b.x*b.x + b.y*b.y + b.z*b.z + b.w*b.w;
    #pragma unroll
    for (int off = 32; off > 0; off >>= 1) s += __shfl_down(s, off, 64);
    if (lane == 0) w2[v] = s;
}

__global__ __launch_bounds__(256) void count_kernel_fb(
        const float* __restrict__ X, const float* __restrict__ W,
        const float* __restrict__ w2, const float* __restrict__ st,
        const int* __restrict__ target, int* __restrict__ count) {
    __shared__ float Xs[BK][BM];
    __shared__ float Ws[BK][BN];
    __shared__ float st_s[BM];
    __shared__ int   t_s[BM];
    __shared__ float w2_s[BN];
    const int tid  = threadIdx.x;
    const int row0 = blockIdx.y * BM;
    const int col0 = blockIdx.x * BN;
    if (tid < 128) { st_s[tid] = st[row0 + tid]; t_s[tid] = target[row0 + tid]; }
    else { int cc = tid - 128; int v = col0 + cc; if (v >= VOCAB) v = VOCAB - 1; w2_s[cc] = w2[v]; }
    float acc[TM][TN] = {};
    const int tx = tid & 15;
    const int ty = tid >> 4;
    for (int k0 = 0; k0 < DIM; k0 += BK) {
        #pragma unroll
        for (int j = 0; j < 2; j++) {
            int idx = tid + 256 * j;
            int r   = idx >> 2;
            int kq  = idx & 3;
            float4 xv = *(const float4*)(X + (size_t)(row0 + r) * DIM + k0 + kq * 4);
            Xs[kq*4+0][r] = xv.x; Xs[kq*4+1][r] = xv.y;
            Xs[kq*4+2][r] = xv.z; Xs[kq*4+3][r] = xv.w;
            int v = col0 + r; if (v >= VOCAB) v = VOCAB - 1;
            float4 wv = *(const float4*)(W + (size_t)v * DIM + k0 + kq * 4);
            Ws[kq*4+0][r] = wv.x; Ws[kq*4+1][r] = wv.y;
            Ws[kq*4+2][r] = wv.z; Ws[kq*4+3][r] = wv.w;
        }
        __syncthreads();
        #pragma unroll
        for (int kk = 0; kk < BK; kk++) {
            float a[TM], b[TN];
            #pragma unroll
            for (int i = 0; i < TM; i++) a[i] = Xs[kk][ty * TM + i];
            #pragma unroll
            for (int j = 0; j < TN; j++) b[j] = Ws[kk][tx * TN + j];
            #pragma unroll
            for (int i = 0; i < TM; i++)
                #pragma unroll
                for (int j = 0; j < TN; j++)
                    acc[i][j] += a[i] * b[j];
        }
        __syncthreads();
    }
    int cnt[TM];
    #pragma unroll
    for (int i = 0; i < TM; i++) {
        cnt[i] = 0;
        float stv = st_s[ty * TM + i];
        int   t   = t_s[ty * TM + i];
        #pragma unroll
        for (int j = 0; j < TN; j++) {
            int v = col0 + tx * TN + j;
            float s = w2_s[tx * TN + j] - 2.0f * acc[i][j];
            if (v < VOCAB && v != t && (s < stv || (s == stv && v < t))) cnt[i]++;
        }
    }
    __syncthreads();
    int* scnt = (int*)Xs;
    #pragma unroll
    for (int i = 0; i < TM; i++) scnt[(ty * TM + i) * 16 + tx] = cnt[i];
    __syncthreads();
    if (tid < BM) {
        int s = 0;
        #pragma unroll
        for (int j = 0; j < 16; j++) s += scnt[tid * 16 + j];
        atomicAdd(&count[row0 + tid], s);
    }
}

__global__ __launch_bounds__(256) void finalize_fb(const int* __restrict__ count,
                                                   const int* __restrict__ mask,
                                                   float* __restrict__ out) {
    int tid = threadIdx.x;
    int hits = 0, msum = 0;
    for (int n = tid; n < N_ROWS; n += 256) {
        int m = mask[n];
        msum += m;
        if (m && count[n] < TOPK) hits++;
    }
    #pragma unroll
    for (int off = 32; off > 0; off >>= 1) {
        hits += __shfl_down(hits, off, 64);
        msum += __shfl_down(msum, off, 64);
    }
    __shared__ int sh[8];
    int wid = tid >> 6, lane = tid & 63;
    if (lane == 0) { sh[wid] = hits; sh[4 + wid] = msum; }
    __syncthreads();
    if (tid == 0) {
        int H = sh[0] + sh[1] + sh[2] + sh[3];
        int M = sh[4] + sh[5] + sh[6] + sh[7];
        out[0] = (float)H / (float)M;
    }
}

// ================= launch =================
extern "C" void kernel_launch(void* const* d_in, const int* in_sizes, int n_in,
                              void* d_out, int out_size, void* d_ws, size_t ws_size,
                              hipStream_t stream) {
    const float* X      = (const float*)d_in[0];
    const int*   target = (const int*)d_in[1];
    const int*   mask   = (const int*)d_in[2];
    const float* W      = (const float*)d_in[3];
    float* out = (float*)d_out;
    char* ws = (char*)d_ws;

    const size_t oXb   = 0;
    const size_t oWb   = oXb  + (size_t)N_ROWS * DIM * 2;   //  4,194,304
    const size_t ow2   = oWb  + (size_t)VPAD  * DIM * 2;    // 51,249,152
    const size_t ost   = ow2  + (size_t)VPAD * 4;
    const size_t ocd   = ost  + (size_t)N_ROWS * 4;
    const size_t ocu   = ocd  + (size_t)N_ROWS * 4;
    const size_t oce   = ocu  + (size_t)N_ROWS * 4;
    const size_t ohit  = oce  + (size_t)N_ROWS * 4;
    const size_t oamb  = ohit + (size_t)N_ROWS * 4;
    const size_t oambc = oamb + (size_t)N_ROWS * 4;
    const size_t need  = oambc + 16;

    if (ws_size >= need) {
        unsigned short* Xb = (unsigned short*)(ws + oXb);
        unsigned short* Wb = (unsigned short*)(ws + oWb);
        float* w2 = (float*)(ws + ow2);
        float* st = (float*)(ws + ost);
        int* cnt_def = (int*)(ws + ocd);
        int* cnt_unc = (int*)(ws + ocu);
        int* count_exact = (int*)(ws + oce);
        int* hit = (int*)(ws + ohit);
        int* amb_rows = (int*)(ws + oamb);
        int* amb_count = (int*)(ws + oambc);

        hipMemsetAsync(ws + ocd, 0, oambc + 16 - ocd, stream);  // cnt_def..amb_count
        convert_x<<<2048, 256, 0, stream>>>(X, Xb);
        convert_w<<<VPAD, 128, 0, stream>>>(W, Wb, w2);
        st_kernel<<<N_ROWS, 64, 0, stream>>>(X, W, target, st);
        count_mfma<<<dim3(N_ROWS / 128, VPAD / 128), 256, 0, stream>>>(
            Xb, Wb, w2, st, target, cnt_def, cnt_unc);
        resolve_kernel<<<16, 256, 0, stream>>>(cnt_def, cnt_unc, hit, amb_rows, amb_count);
        exact_kernel<<<256, 256, 0, stream>>>(X, W, w2, st, target, amb_rows, amb_count, count_exact);
        finalize2<<<1, 256, 0, stream>>>(hit, count_exact, mask, out);
    } else {
        float* w2 = (float*)ws;                       // 50000 f -> 200704 B padded
        float* st = (float*)(ws + 200704);
        int* countp = (int*)(ws + 200704 + 16384);
        hipMemsetAsync(countp, 0, N_ROWS * sizeof(int), stream);
        w2_kernel_fb<<<VOCAB, 64, 0, stream>>>(W, w2);
        st_kernel<<<N_ROWS, 64, 0, stream>>>(X, W, target, st);
        dim3 grid((VOCAB + BN - 1) / BN, N_ROWS / BM);
        count_kernel_fb<<<grid, 256, 0, stream>>>(X, W, w2, st, target, countp);
        finalize_fb<<<1, 256, 0, stream>>>(countp, mask, out);
    }
}

// Round 3
// 542.228 us; speedup vs baseline: 4.5615x; 1.5791x over previous
//
#include <hip/hip_runtime.h>
#include <stdint.h>

#define N_ROWS 4096
#define DIM    512
#define VOCAB  50000
#define VPAD   50048
#define TOPK   10
#define MARGIN 2.0f
#define ECHUNKS 196            // chunks of 256 words per ambiguous row (196*256=50176)

typedef short bf16x8 __attribute__((ext_vector_type(8)));
typedef float f32x4  __attribute__((ext_vector_type(4)));

#define GLOBAL_AS __attribute__((address_space(1)))
#define LDS_AS    __attribute__((address_space(3)))

__device__ __forceinline__ unsigned short f2bf(float f) {
    unsigned int u = __float_as_uint(f);
    u += 0x7fff + ((u >> 16) & 1);          // round-to-nearest-even
    return (unsigned short)(u >> 16);
}

// ---------------- fp32 -> bf16 conversion ----------------
__global__ __launch_bounds__(256) void convert_x(const float* __restrict__ X,
                                                 unsigned short* __restrict__ Xb) {
    int idx = blockIdx.x * 256 + threadIdx.x;            // 4 elems per thread
    float4 f = ((const float4*)X)[idx];
    ((ushort4*)Xb)[idx] = make_ushort4(f2bf(f.x), f2bf(f.y), f2bf(f.z), f2bf(f.w));
}

// one block (128 thr) per word row: convert + w2 (fp32 exact). Pad rows: zeros, w2=1e30.
__global__ __launch_bounds__(128) void convert_w(const float* __restrict__ W,
                                                 unsigned short* __restrict__ Wb,
                                                 float* __restrict__ w2) {
    int v = blockIdx.x, tid = threadIdx.x;
    __shared__ float sh[2];
    if (v < VOCAB) {
        float4 f = ((const float4*)(W + (size_t)v * DIM))[tid];
        ((ushort4*)(Wb + (size_t)v * DIM))[tid] =
            make_ushort4(f2bf(f.x), f2bf(f.y), f2bf(f.z), f2bf(f.w));
        float s = f.x*f.x + f.y*f.y + f.z*f.z + f.w*f.w;
        #pragma unroll
        for (int off = 32; off > 0; off >>= 1) s += __shfl_down(s, off, 64);
        if ((tid & 63) == 0) sh[tid >> 6] = s;
        __syncthreads();
        if (tid == 0) w2[v] = sh[0] + sh[1];
    } else {
        ((ushort4*)(Wb + (size_t)v * DIM))[tid] = make_ushort4(0, 0, 0, 0);
        if (tid == 0) w2[v] = 1e30f;
    }
}

// ---------- st[n] = ||w_t||^2 - 2 x_n . w_t (fp32 exact) ----------
__global__ __launch_bounds__(64) void st_kernel(const float* __restrict__ X,
                                                const float* __restrict__ W,
                                                const int* __restrict__ target,
                                                float* __restrict__ st) {
    int n = blockIdx.x;
    int t = target[n];
    const float4* x4 = (const float4*)(X + (size_t)n * DIM);
    const float4* w4 = (const float4*)(W + (size_t)t * DIM);
    int lane = threadIdx.x;
    float4 xa = x4[lane], xb = x4[lane + 64];
    float4 wa = w4[lane], wb = w4[lane + 64];
    float sxw = xa.x*wa.x + xa.y*wa.y + xa.z*wa.z + xa.w*wa.w
              + xb.x*wb.x + xb.y*wb.y + xb.z*wb.z + xb.w*wb.w;
    float sww = wa.x*wa.x + wa.y*wa.y + wa.z*wa.z + wa.w*wa.w
              + wb.x*wb.x + wb.y*wb.y + wb.z*wb.z + wb.w*wb.w;
    #pragma unroll
    for (int off = 32; off > 0; off >>= 1) {
        sxw += __shfl_down(sxw, off, 64);
        sww += __shfl_down(sww, off, 64);
    }
    if (lane == 0) st[n] = sww - 2.0f * sxw;
}

// ---------------- bf16 MFMA GEMM + band-count ----------------
// 128x128 tile, BK=32, 4 waves (2x2), mfma_f32_16x16x32_bf16, 4x4 frags/wave.
__global__ __launch_bounds__(256) void count_mfma(
        const unsigned short* __restrict__ Xb, const unsigned short* __restrict__ Wb,
        const float* __restrict__ w2, const float* __restrict__ st,
        const int* __restrict__ target,
        int* __restrict__ cnt_def, int* __restrict__ cnt_unc) {

    __shared__ unsigned short Als[128 * 32];
    __shared__ unsigned short Bls[128 * 32];
    __shared__ float w2_s[128];
    __shared__ float st_s[128];
    __shared__ int   t_s[128];
    __shared__ int   pk_s[128];

    const int tid  = threadIdx.x;
    const int wave = tid >> 6, lane = tid & 63;
    const int row0 = blockIdx.x * 128;          // x fastest -> W-tile reuse across 32 blocks
    const int col0 = blockIdx.y * 128;

    if (tid < 128) { w2_s[tid] = w2[col0 + tid]; pk_s[tid] = 0; }
    else           { st_s[tid - 128] = st[row0 + tid - 128];
                     t_s[tid - 128]  = target[row0 + tid - 128]; }

    // staging: each wave stages 32 rows of A and of B; lane -> (row, 16B chunk)
    const unsigned short* ga = Xb + (size_t)(row0 + wave*32 + (lane >> 2)) * DIM + (lane & 3) * 8;
    const unsigned short* gb = Wb + (size_t)(col0 + wave*32 + (lane >> 2)) * DIM + (lane & 3) * 8;
    unsigned short* la0 = &Als[(wave*32     ) * 32];
    unsigned short* la1 = &Als[(wave*32 + 16) * 32];
    unsigned short* lb0 = &Bls[(wave*32     ) * 32];
    unsigned short* lb1 = &Bls[(wave*32 + 16) * 32];

    const int q = lane >> 4, c = lane & 15;     // quad, col-in-16
    const int wm = wave >> 1, wn = wave & 1;
    const unsigned short* ap = &Als[(wm*64 + c) * 32 + q * 8];
    const unsigned short* bp = &Bls[(wn*64 + c) * 32 + q * 8];

    f32x4 acc[4][4];
    #pragma unroll
    for (int i = 0; i < 4; i++)
        #pragma unroll
        for (int j = 0; j < 4; j++) acc[i][j] = (f32x4){0.f, 0.f, 0.f, 0.f};

    for (int k0 = 0; k0 < DIM; k0 += 32) {
        __builtin_amdgcn_global_load_lds((const GLOBAL_AS void*)(ga + k0),           (LDS_AS void*)la0, 16, 0, 0);
        __builtin_amdgcn_global_load_lds((const GLOBAL_AS void*)(ga + 16*DIM + k0),  (LDS_AS void*)la1, 16, 0, 0);
        __builtin_amdgcn_global_load_lds((const GLOBAL_AS void*)(gb + k0),           (LDS_AS void*)lb0, 16, 0, 0);
        __builtin_amdgcn_global_load_lds((const GLOBAL_AS void*)(gb + 16*DIM + k0),  (LDS_AS void*)lb1, 16, 0, 0);
        __syncthreads();
        bf16x8 af[4], bfr[4];
        #pragma unroll
        for (int i = 0; i < 4; i++) af[i]  = *(const bf16x8*)(ap + i * 16 * 32);
        #pragma unroll
        for (int j = 0; j < 4; j++) bfr[j] = *(const bf16x8*)(bp + j * 16 * 32);
        #pragma unroll
        for (int i = 0; i < 4; i++)
            #pragma unroll
            for (int j = 0; j < 4; j++)
                acc[i][j] = __builtin_amdgcn_mfma_f32_16x16x32_bf16(af[i], bfr[j], acc[i][j], 0, 0, 0);
        __syncthreads();
    }

    // epilogue: banded compare-count, no C write. C/D: col=lane&15, row=q*4+reg.
    #pragma unroll
    for (int i = 0; i < 4; i++) {
        #pragma unroll
        for (int reg = 0; reg < 4; reg++) {
            int r = wm*64 + i*16 + q*4 + reg;
            float stv = st_s[r];
            int   t   = t_s[r];
            int def = 0, unc = 0;
            #pragma unroll
            for (int j = 0; j < 4; j++) {
                int col_l = wn*64 + j*16 + c;
                float s = w2_s[col_l] - 2.0f * acc[i][j][reg];
                int v = col0 + col_l;                 // pad cols: w2=1e30 -> never counted
                if (v != t) {
                    if      (s < stv - MARGIN) def++;
                    else if (s < stv + MARGIN) unc++;
                }
            }
            int pk = (def << 16) | unc;               // per-block <=128 each: fits
            pk += __shfl_xor(pk, 1, 64);
            pk += __shfl_xor(pk, 2, 64);
            pk += __shfl_xor(pk, 4, 64);
            pk += __shfl_xor(pk, 8, 64);
            if (c == 0) atomicAdd(&pk_s[r], pk);
        }
    }
    __syncthreads();
    if (tid < 128) {
        int pk = pk_s[tid];
        if (pk) {
            atomicAdd(&cnt_def[row0 + tid], pk >> 16);
            atomicAdd(&cnt_unc[row0 + tid], pk & 0xffff);
        }
    }
}

// ---------------- resolve: definite rows -> hit, ambiguous -> list ----------------
__global__ __launch_bounds__(256) void resolve_kernel(const int* __restrict__ cnt_def,
                                                      const int* __restrict__ cnt_unc,
                                                      int* __restrict__ hit,
                                                      int* __restrict__ amb_rows,
                                                      int* __restrict__ amb_count) {
    int n = blockIdx.x * 256 + threadIdx.x;
    if (n >= N_ROWS) return;
    int d = cnt_def[n], u = cnt_unc[n];
    int h;
    if (d >= TOPK) h = 0;
    else if (d + u < TOPK) h = 1;
    else { int idx = atomicAdd(amb_count, 1); amb_rows[idx] = n; h = 2; }
    hit[n] = h;
}

// ---------------- exact fp32 recount, highly parallel ----------------
// grid-stride over (row, chunk) with ECHUNKS=196 chunks of 256 words per row.
// Block = 4 waves; each wave serially handles 64 words; the 64 lanes split the
// 512-dim dot (lane i owns dims 8i..8i+7 -> coalesced 32 B/lane), butterfly reduce.
__global__ __launch_bounds__(256) void exact_kernel(const float* __restrict__ X,
                                                    const float* __restrict__ W,
                                                    const float* __restrict__ w2,
                                                    const float* __restrict__ st,
                                                    const int* __restrict__ target,
                                                    const int* __restrict__ amb_rows,
                                                    const int* __restrict__ amb_count,
                                                    int* __restrict__ count_exact) {
    __shared__ float xs[DIM];
    __shared__ int scnt[4];
    const int tid = threadIdx.x, wave = tid >> 6, lane = tid & 63;
    const int nw = amb_count[0] * ECHUNKS;
    for (int w = blockIdx.x; w < nw; w += gridDim.x) {
        const int row   = amb_rows[w / ECHUNKS];
        const int chunk = w % ECHUNKS;
        __syncthreads();                    // xs reuse barrier across grid-stride iters
        for (int i = tid; i < DIM; i += 256) xs[i] = X[(size_t)row * DIM + i];
        if (tid < 4) scnt[tid] = 0;
        __syncthreads();
        const float4 xa = *(const float4*)&xs[lane * 8];
        const float4 xb = *(const float4*)&xs[lane * 8 + 4];
        const float stv = st[row];
        const int   t   = target[row];
        int cnt = 0;
        const int v0 = chunk * 256 + wave * 64;
        #pragma unroll 2
        for (int i = 0; i < 64; i++) {
            int v = v0 + i;
            if (v < VOCAB) {
                const float4* wr = (const float4*)(W + (size_t)v * DIM + lane * 8);
                float4 wa = wr[0], wb = wr[1];
                float p = xa.x*wa.x + xa.y*wa.y + xa.z*wa.z + xa.w*wa.w
                        + xb.x*wb.x + xb.y*wb.y + xb.z*wb.z + xb.w*wb.w;
                p += __shfl_xor(p, 1, 64);
                p += __shfl_xor(p, 2, 64);
                p += __shfl_xor(p, 4, 64);
                p += __shfl_xor(p, 8, 64);
                p += __shfl_xor(p, 16, 64);
                p += __shfl_xor(p, 32, 64);
                float s = w2[v] - 2.0f * p;
                if (lane == 0 && v != t && (s < stv || (s == stv && v < t))) cnt++;
            }
        }
        if (lane == 0) scnt[wave] = cnt;
        __syncthreads();
        if (tid == 0)
            atomicAdd(&count_exact[row], scnt[0] + scnt[1] + scnt[2] + scnt[3]);
    }
}

// ---------------- final reduction ----------------
__global__ __launch_bounds__(256) void finalize2(const int* __restrict__ hit,
                                                 const int* __restrict__ count_exact,
                                                 const int* __restrict__ mask,
                                                 float* __restrict__ out) {
    int tid = threadIdx.x;
    int hits = 0, msum = 0;
    for (int n = tid; n < N_ROWS; n += 256) {
        int m = mask[n];
        msum += m;
        int h = hit[n];
        int hv = (h == 2) ? (count_exact[n] < TOPK ? 1 : 0) : h;
        if (m) hits += hv;
    }
    #pragma unroll
    for (int off = 32; off > 0; off >>= 1) {
        hits += __shfl_down(hits, off, 64);
        msum += __shfl_down(msum, off, 64);
    }
    __shared__ int sh[8];
    int wid = tid >> 6, lane = tid & 63;
    if (lane == 0) { sh[wid] = hits; sh[4 + wid] = msum; }
    __syncthreads();
    if (tid == 0) {
        int H = sh[0] + sh[1] + sh[2] + sh[3];
        int M = sh[4] + sh[5] + sh[6] + sh[7];
        out[0] = (float)H / (float)M;
    }
}

// ================= round-1 verified fp32 fallback (if ws too small) =================
#define BM 128
#define BN 128
#define BK 16
#define TM 8
#define TN 8

__global__ __launch_bounds__(64) void w2_kernel_fb(const float* __restrict__ W,
                                                   float* __restrict__ w2) {
    int v = blockIdx.x;
    const float4* w4 = (const float4*)(W + (size_t)v * DIM);
    int lane = threadIdx.x;
    float4 a = w4[lane];
    float4 b = w4[lane + 64];
    float s = a.x*a.x + a.y*a.y + a.z*a.z + a.w*a.w
            + b.x*b.x + b.y*b.y + b.z*b.z + b.w*b.w;
    #pragma unroll
    for (int off = 32; off > 0; off >>= 1) s += __shfl_down(s, off, 64);
    if (lane == 0) w2[v] = s;
}

__global__ __launch_bounds__(256) void count_kernel_fb(
        const float* __restrict__ X, const float* __restrict__ W,
        const float* __restrict__ w2, const float* __restrict__ st,
        const int* __restrict__ target, int* __restrict__ count) {
    __shared__ float Xs[BK][BM];
    __shared__ float Ws[BK][BN];
    __shared__ float st_s[BM];
    __shared__ int   t_s[BM];
    __shared__ float w2_s[BN];
    const int tid  = threadIdx.x;
    const int row0 = blockIdx.y * BM;
    const int col0 = blockIdx.x * BN;
    if (tid < 128) { st_s[tid] = st[row0 + tid]; t_s[tid] = target[row0 + tid]; }
    else { int cc = tid - 128; int v = col0 + cc; if (v >= VOCAB) v = VOCAB - 1; w2_s[cc] = w2[v]; }
    float acc[TM][TN] = {};
    const int tx = tid & 15;
    const int ty = tid >> 4;
    for (int k0 = 0; k0 < DIM; k0 += BK) {
        #pragma unroll
        for (int j = 0; j < 2; j++) {
            int idx = tid + 256 * j;
            int r   = idx >> 2;
            int kq  = idx & 3;
            float4 xv = *(const float4*)(X + (size_t)(row0 + r) * DIM + k0 + kq * 4);
            Xs[kq*4+0][r] = xv.x; Xs[kq*4+1][r] = xv.y;
            Xs[kq*4+2][r] = xv.z; Xs[kq*4+3][r] = xv.w;
            int v = col0 + r; if (v >= VOCAB) v = VOCAB - 1;
            float4 wv = *(const float4*)(W + (size_t)v * DIM + k0 + kq * 4);
            Ws[kq*4+0][r] = wv.x; Ws[kq*4+1][r] = wv.y;
            Ws[kq*4+2][r] = wv.z; Ws[kq*4+3][r] = wv.w;
        }
        __syncthreads();
        #pragma unroll
        for (int kk = 0; kk < BK; kk++) {
            float a[TM], b[TN];
            #pragma unroll
            for (int i = 0; i < TM; i++) a[i] = Xs[kk][ty * TM + i];
            #pragma unroll
            for (int j = 0; j < TN; j++) b[j] = Ws[kk][tx * TN + j];
            #pragma unroll
            for (int i = 0; i < TM; i++)
                #pragma unroll
                for (int j = 0; j < TN; j++)
                    acc[i][j] += a[i] * b[j];
        }
        __syncthreads();
    }
    int cnt[TM];
    #pragma unroll
    for (int i = 0; i < TM; i++) {
        cnt[i] = 0;
        float stv = st_s[ty * TM + i];
        int   t   = t_s[ty * TM + i];
        #pragma unroll
        for (int j = 0; j < TN; j++) {
            int v = col0 + tx * TN + j;
            float s = w2_s[tx * TN + j] - 2.0f * acc[i][j];
            if (v < VOCAB && v != t && (s < stv || (s == stv && v < t))) cnt[i]++;
        }
    }
    __syncthreads();
    int* scnt = (int*)Xs;
    #pragma unroll
    for (int i = 0; i < TM; i++) scnt[(ty * TM + i) * 16 + tx] = cnt[i];
    __syncthreads();
    if (tid < BM) {
        int s = 0;
        #pragma unroll
        for (int j = 0; j < 16; j++) s += scnt[tid * 16 + j];
        atomicAdd(&count[row0 + tid], s);
    }
}

__global__ __launch_bounds__(256) void finalize_fb(const int* __restrict__ count,
                                                   const int* __restrict__ mask,
                                                   float* __restrict__ out) {
    int tid = threadIdx.x;
    int hits = 0, msum = 0;
    for (int n = tid; n < N_ROWS; n += 256) {
        int m = mask[n];
        msum += m;
        if (m && count[n] < TOPK) hits++;
    }
    #pragma unroll
    for (int off = 32; off > 0; off >>= 1) {
        hits += __shfl_down(hits, off, 64);
        msum += __shfl_down(msum, off, 64);
    }
    __shared__ int sh[8];
    int wid = tid >> 6, lane = tid & 63;
    if (lane == 0) { sh[wid] = hits; sh[4 + wid] = msum; }
    __syncthreads();
    if (tid == 0) {
        int H = sh[0] + sh[1] + sh[2] + sh[3];
        int M = sh[4] + sh[5] + sh[6] + sh[7];
        out[0] = (float)H / (float)M;
    }
}

// ================= launch =================
extern "C" void kernel_launch(void* const* d_in, const int* in_sizes, int n_in,
                              void* d_out, int out_size, void* d_ws, size_t ws_size,
                              hipStream_t stream) {
    const float* X      = (const float*)d_in[0];
    const int*   target = (const int*)d_in[1];
    const int*   mask   = (const int*)d_in[2];
    const float* W      = (const float*)d_in[3];
    float* out = (float*)d_out;
    char* ws = (char*)d_ws;

    const size_t oXb   = 0;
    const size_t oWb   = oXb  + (size_t)N_ROWS * DIM * 2;   //  4,194,304
    const size_t ow2   = oWb  + (size_t)VPAD  * DIM * 2;    // 51,249,152
    const size_t ost   = ow2  + (size_t)VPAD * 4;
    const size_t ocd   = ost  + (size_t)N_ROWS * 4;
    const size_t ocu   = ocd  + (size_t)N_ROWS * 4;
    const size_t oce   = ocu  + (size_t)N_ROWS * 4;
    const size_t ohit  = oce  + (size_t)N_ROWS * 4;
    const size_t oamb  = ohit + (size_t)N_ROWS * 4;
    const size_t oambc = oamb + (size_t)N_ROWS * 4;
    const size_t need  = oambc + 16;

    if (ws_size >= need) {
        unsigned short* Xb = (unsigned short*)(ws + oXb);
        unsigned short* Wb = (unsigned short*)(ws + oWb);
        float* w2 = (float*)(ws + ow2);
        float* st = (float*)(ws + ost);
        int* cnt_def = (int*)(ws + ocd);
        int* cnt_unc = (int*)(ws + ocu);
        int* count_exact = (int*)(ws + oce);
        int* hit = (int*)(ws + ohit);
        int* amb_rows = (int*)(ws + oamb);
        int* amb_count = (int*)(ws + oambc);

        hipMemsetAsync(ws + ocd, 0, oambc + 16 - ocd, stream);  // cnt_def..amb_count
        convert_x<<<2048, 256, 0, stream>>>(X, Xb);
        convert_w<<<VPAD, 128, 0, stream>>>(W, Wb, w2);
        st_kernel<<<N_ROWS, 64, 0, stream>>>(X, W, target, st);
        count_mfma<<<dim3(N_ROWS / 128, VPAD / 128), 256, 0, stream>>>(
            Xb, Wb, w2, st, target, cnt_def, cnt_unc);
        resolve_kernel<<<16, 256, 0, stream>>>(cnt_def, cnt_unc, hit, amb_rows, amb_count);
        exact_kernel<<<2048, 256, 0, stream>>>(X, W, w2, st, target, amb_rows, amb_count, count_exact);
        finalize2<<<1, 256, 0, stream>>>(hit, count_exact, mask, out);
    } else {
        float* w2 = (float*)ws;                       // 50000 f -> 200704 B padded
        float* st = (float*)(ws + 200704);
        int* countp = (int*)(ws + 200704 + 16384);
        hipMemsetAsync(countp, 0, N_ROWS * sizeof(int), stream);
        w2_kernel_fb<<<VOCAB, 64, 0, stream>>>(W, w2);
        st_kernel<<<N_ROWS, 64, 0, stream>>>(X, W, target, st);
        dim3 grid((VOCAB + BN - 1) / BN, N_ROWS / BM);
        count_kernel_fb<<<grid, 256, 0, stream>>>(X, W, w2, st, target, countp);
        finalize_fb<<<1, 256, 0, stream>>>(countp, mask, out);
    }
}

// Round 4
// 457.869 us; speedup vs baseline: 5.4019x; 1.1842x over previous
//
#include <hip/hip_runtime.h>
#include <stdint.h>

#define N_ROWS 4096
#define DIM    512
#define VOCAB  50000
#define VPAD   50048
#define TOPK   10
#define MARGIN 8.0f            // i8 band: >=13 sigma of quantization error
#define ECHUNKS 196            // chunks of 256 words per ambiguous row (196*256=50176)

typedef int   i32x4 __attribute__((ext_vector_type(4)));
typedef float f32x4 __attribute__((ext_vector_type(4)));

#define GLOBAL_AS __attribute__((address_space(1)))
#define LDS_AS    __attribute__((address_space(3)))

// ---------------- per-row int8 quantization ----------------
// wave per row: lane owns 8 consecutive floats; rowmax via butterfly; exact fp32 w2.
__device__ __forceinline__ void quant_row(const float* __restrict__ src,
                                          signed char* __restrict__ dst,
                                          int lane, float* rowmax_out,
                                          float* w2_out) {
    const float4* s4 = (const float4*)(src + lane * 8);
    float4 a = s4[0], b = s4[1];
    float mx = fmaxf(fmaxf(fmaxf(fabsf(a.x), fabsf(a.y)), fmaxf(fabsf(a.z), fabsf(a.w))),
                     fmaxf(fmaxf(fabsf(b.x), fabsf(b.y)), fmaxf(fabsf(b.z), fabsf(b.w))));
    float w2 = a.x*a.x + a.y*a.y + a.z*a.z + a.w*a.w
             + b.x*b.x + b.y*b.y + b.z*b.z + b.w*b.w;
    #pragma unroll
    for (int off = 1; off < 64; off <<= 1) {
        mx  = fmaxf(mx, __shfl_xor(mx, off, 64));
        w2 += __shfl_xor(w2, off, 64);
    }
    float inv = 127.0f / fmaxf(mx, 1e-30f);
    int q0 = (int)rintf(a.x * inv), q1 = (int)rintf(a.y * inv);
    int q2 = (int)rintf(a.z * inv), q3 = (int)rintf(a.w * inv);
    int q4 = (int)rintf(b.x * inv), q5 = (int)rintf(b.y * inv);
    int q6 = (int)rintf(b.z * inv), q7 = (int)rintf(b.w * inv);
    uint2 pk;
    pk.x = (q0 & 0xff) | ((q1 & 0xff) << 8) | ((q2 & 0xff) << 16) | ((unsigned)(q3 & 0xff) << 24);
    pk.y = (q4 & 0xff) | ((q5 & 0xff) << 8) | ((q6 & 0xff) << 16) | ((unsigned)(q7 & 0xff) << 24);
    *(uint2*)(dst + lane * 8) = pk;
    *rowmax_out = mx;
    *w2_out = w2;
}

__global__ __launch_bounds__(256) void quantize_x(const float* __restrict__ X,
                                                  signed char* __restrict__ Xq,
                                                  float* __restrict__ sx) {
    int wave = threadIdx.x >> 6, lane = threadIdx.x & 63;
    int row = blockIdx.x * 4 + wave;
    float mx, w2;
    quant_row(X + (size_t)row * DIM, Xq + (size_t)row * DIM, lane, &mx, &w2);
    if (lane == 0) sx[row] = fmaxf(mx, 1e-30f) / 127.0f;
}

__global__ __launch_bounds__(256) void quantize_w(const float* __restrict__ W,
                                                  signed char* __restrict__ Wq,
                                                  float* __restrict__ sw,
                                                  float* __restrict__ w2) {
    int wave = threadIdx.x >> 6, lane = threadIdx.x & 63;
    int row = blockIdx.x * 4 + wave;
    if (row < VOCAB) {
        float mx, s2;
        quant_row(W + (size_t)row * DIM, Wq + (size_t)row * DIM, lane, &mx, &s2);
        if (lane == 0) { sw[row] = fmaxf(mx, 1e-30f) / 127.0f; w2[row] = s2; }
    } else {
        *(uint2*)(Wq + (size_t)row * DIM + lane * 8) = make_uint2(0, 0);
        if (lane == 0) { sw[row] = 0.0f; w2[row] = 1e30f; }
    }
}

// ---------- st[n] = ||w_t||^2 - 2 x_n . w_t (fp32 exact) ----------
__global__ __launch_bounds__(64) void st_kernel(const float* __restrict__ X,
                                                const float* __restrict__ W,
                                                const int* __restrict__ target,
                                                float* __restrict__ st) {
    int n = blockIdx.x;
    int t = target[n];
    const float4* x4 = (const float4*)(X + (size_t)n * DIM);
    const float4* w4 = (const float4*)(W + (size_t)t * DIM);
    int lane = threadIdx.x;
    float4 xa = x4[lane], xb = x4[lane + 64];
    float4 wa = w4[lane], wb = w4[lane + 64];
    float sxw = xa.x*wa.x + xa.y*wa.y + xa.z*wa.z + xa.w*wa.w
              + xb.x*wb.x + xb.y*wb.y + xb.z*wb.z + xb.w*wb.w;
    float sww = wa.x*wa.x + wa.y*wa.y + wa.z*wa.z + wa.w*wa.w
              + wb.x*wb.x + wb.y*wb.y + wb.z*wb.z + wb.w*wb.w;
    #pragma unroll
    for (int off = 32; off > 0; off >>= 1) {
        sxw += __shfl_down(sxw, off, 64);
        sww += __shfl_down(sww, off, 64);
    }
    if (lane == 0) st[n] = sww - 2.0f * sxw;
}

// ---------------- i8 MFMA GEMM + band-count ----------------
// 128x128 tile, BK=64 (bytes), 4 waves (2x2), mfma_i32_16x16x64_i8, 4x4 frags/wave.
// Staging geometry identical to the verified bf16 kernel (64 B/row/iter).
__global__ __launch_bounds__(256) void count_mfma_i8(
        const signed char* __restrict__ Xq, const signed char* __restrict__ Wq,
        const float* __restrict__ sx, const float* __restrict__ sw,
        const float* __restrict__ w2, const float* __restrict__ st,
        const int* __restrict__ target,
        int* __restrict__ cnt_def, int* __restrict__ cnt_unc) {

    __shared__ signed char Als[128 * 64];
    __shared__ signed char Bls[128 * 64];
    __shared__ float w2_s[128];
    __shared__ float sw_s[128];
    __shared__ float st_s[128];
    __shared__ float sx_s[128];
    __shared__ int   t_s[128];
    __shared__ int   pk_s[128];

    const int tid  = threadIdx.x;
    const int wave = tid >> 6, lane = tid & 63;
    const int row0 = blockIdx.x * 128;          // x fastest -> W-tile reuse across 32 blocks
    const int col0 = blockIdx.y * 128;

    if (tid < 128) { w2_s[tid] = w2[col0 + tid]; sw_s[tid] = sw[col0 + tid]; pk_s[tid] = 0; }
    else           { st_s[tid - 128] = st[row0 + tid - 128];
                     sx_s[tid - 128] = sx[row0 + tid - 128];
                     t_s[tid - 128]  = target[row0 + tid - 128]; }

    // staging: each wave stages 32 rows of A and of B; lane -> (row, 16B chunk)
    const signed char* ga = Xq + (size_t)(row0 + wave*32 + (lane >> 2)) * DIM + (lane & 3) * 16;
    const signed char* gb = Wq + (size_t)(col0 + wave*32 + (lane >> 2)) * DIM + (lane & 3) * 16;
    signed char* la0 = &Als[(wave*32     ) * 64];
    signed char* la1 = &Als[(wave*32 + 16) * 64];
    signed char* lb0 = &Bls[(wave*32     ) * 64];
    signed char* lb1 = &Bls[(wave*32 + 16) * 64];

    const int q = lane >> 4, c = lane & 15;     // quad, col-in-16
    const int wm = wave >> 1, wn = wave & 1;
    const signed char* ap = &Als[(wm*64 + c) * 64 + q * 16];
    const signed char* bp = &Bls[(wn*64 + c) * 64 + q * 16];

    i32x4 acc[4][4];
    #pragma unroll
    for (int i = 0; i < 4; i++)
        #pragma unroll
        for (int j = 0; j < 4; j++) acc[i][j] = (i32x4){0, 0, 0, 0};

    for (int k0 = 0; k0 < DIM; k0 += 64) {
        __builtin_amdgcn_global_load_lds((const GLOBAL_AS void*)(ga + k0),           (LDS_AS void*)la0, 16, 0, 0);
        __builtin_amdgcn_global_load_lds((const GLOBAL_AS void*)(ga + 16*DIM + k0),  (LDS_AS void*)la1, 16, 0, 0);
        __builtin_amdgcn_global_load_lds((const GLOBAL_AS void*)(gb + k0),           (LDS_AS void*)lb0, 16, 0, 0);
        __builtin_amdgcn_global_load_lds((const GLOBAL_AS void*)(gb + 16*DIM + k0),  (LDS_AS void*)lb1, 16, 0, 0);
        __syncthreads();
        i32x4 af[4], bfr[4];
        #pragma unroll
        for (int i = 0; i < 4; i++) af[i]  = *(const i32x4*)(ap + i * 16 * 64);
        #pragma unroll
        for (int j = 0; j < 4; j++) bfr[j] = *(const i32x4*)(bp + j * 16 * 64);
        #pragma unroll
        for (int i = 0; i < 4; i++)
            #pragma unroll
            for (int j = 0; j < 4; j++)
                acc[i][j] = __builtin_amdgcn_mfma_i32_16x16x64_i8(af[i], bfr[j], acc[i][j], 0, 0, 0);
        __syncthreads();
    }

    // epilogue: banded compare-count. C/D: col=lane&15, row=q*4+reg (dtype-independent).
    #pragma unroll
    for (int i = 0; i < 4; i++) {
        #pragma unroll
        for (int reg = 0; reg < 4; reg++) {
            int r = wm*64 + i*16 + q*4 + reg;
            float stv = st_s[r];
            float sxr = sx_s[r];
            int   t   = t_s[r];
            int def = 0, unc = 0;
            #pragma unroll
            for (int j = 0; j < 4; j++) {
                int col_l = wn*64 + j*16 + c;
                float dot = sxr * sw_s[col_l] * (float)acc[i][j][reg];
                float s = w2_s[col_l] - 2.0f * dot;
                int v = col0 + col_l;                 // pad cols: w2=1e30 -> never counted
                if (v != t) {
                    if      (s < stv - MARGIN) def++;
                    else if (s < stv + MARGIN) unc++;
                }
            }
            int pk = (def << 16) | unc;               // per-block <=128 each: fits
            pk += __shfl_xor(pk, 1, 64);
            pk += __shfl_xor(pk, 2, 64);
            pk += __shfl_xor(pk, 4, 64);
            pk += __shfl_xor(pk, 8, 64);
            if (c == 0) atomicAdd(&pk_s[r], pk);
        }
    }
    __syncthreads();
    if (tid < 128) {
        int pk = pk_s[tid];
        if (pk) {
            atomicAdd(&cnt_def[row0 + tid], pk >> 16);
            atomicAdd(&cnt_unc[row0 + tid], pk & 0xffff);
        }
    }
}

// ---------------- resolve: definite rows -> hit, ambiguous -> list ----------------
__global__ __launch_bounds__(256) void resolve_kernel(const int* __restrict__ cnt_def,
                                                      const int* __restrict__ cnt_unc,
                                                      int* __restrict__ hit,
                                                      int* __restrict__ amb_rows,
                                                      int* __restrict__ amb_count) {
    int n = blockIdx.x * 256 + threadIdx.x;
    if (n >= N_ROWS) return;
    int d = cnt_def[n], u = cnt_unc[n];
    int h;
    if (d >= TOPK) h = 0;
    else if (d + u < TOPK) h = 1;
    else { int idx = atomicAdd(amb_count, 1); amb_rows[idx] = n; h = 2; }
    hit[n] = h;
}

// ---------------- exact fp32 recount, highly parallel ----------------
__global__ __launch_bounds__(256) void exact_kernel(const float* __restrict__ X,
                                                    const float* __restrict__ W,
                                                    const float* __restrict__ w2,
                                                    const float* __restrict__ st,
                                                    const int* __restrict__ target,
                                                    const int* __restrict__ amb_rows,
                                                    const int* __restrict__ amb_count,
                                                    int* __restrict__ count_exact) {
    __shared__ float xs[DIM];
    __shared__ int scnt[4];
    const int tid = threadIdx.x, wave = tid >> 6, lane = tid & 63;
    const int nw = amb_count[0] * ECHUNKS;
    for (int w = blockIdx.x; w < nw; w += gridDim.x) {
        const int row   = amb_rows[w / ECHUNKS];
        const int chunk = w % ECHUNKS;
        __syncthreads();                    // xs reuse barrier across grid-stride iters
        for (int i = tid; i < DIM; i += 256) xs[i] = X[(size_t)row * DIM + i];
        if (tid < 4) scnt[tid] = 0;
        __syncthreads();
        const float4 xa = *(const float4*)&xs[lane * 8];
        const float4 xb = *(const float4*)&xs[lane * 8 + 4];
        const float stv = st[row];
        const int   t   = target[row];
        int cnt = 0;
        const int v0 = chunk * 256 + wave * 64;
        #pragma unroll 2
        for (int i = 0; i < 64; i++) {
            int v = v0 + i;
            if (v < VOCAB) {
                const float4* wr = (const float4*)(W + (size_t)v * DIM + lane * 8);
                float4 wa = wr[0], wb = wr[1];
                float p = xa.x*wa.x + xa.y*wa.y + xa.z*wa.z + xa.w*wa.w
                        + xb.x*wb.x + xb.y*wb.y + xb.z*wb.z + xb.w*wb.w;
                p += __shfl_xor(p, 1, 64);
                p += __shfl_xor(p, 2, 64);
                p += __shfl_xor(p, 4, 64);
                p += __shfl_xor(p, 8, 64);
                p += __shfl_xor(p, 16, 64);
                p += __shfl_xor(p, 32, 64);
                float s = w2[v] - 2.0f * p;
                if (lane == 0 && v != t && (s < stv || (s == stv && v < t))) cnt++;
            }
        }
        if (lane == 0) scnt[wave] = cnt;
        __syncthreads();
        if (tid == 0)
            atomicAdd(&count_exact[row], scnt[0] + scnt[1] + scnt[2] + scnt[3]);
    }
}

// ---------------- final reduction ----------------
__global__ __launch_bounds__(256) void finalize2(const int* __restrict__ hit,
                                                 const int* __restrict__ count_exact,
                                                 const int* __restrict__ mask,
                                                 float* __restrict__ out) {
    int tid = threadIdx.x;
    int hits = 0, msum = 0;
    for (int n = tid; n < N_ROWS; n += 256) {
        int m = mask[n];
        msum += m;
        int h = hit[n];
        int hv = (h == 2) ? (count_exact[n] < TOPK ? 1 : 0) : h;
        if (m) hits += hv;
    }
    #pragma unroll
    for (int off = 32; off > 0; off >>= 1) {
        hits += __shfl_down(hits, off, 64);
        msum += __shfl_down(msum, off, 64);
    }
    __shared__ int sh[8];
    int wid = tid >> 6, lane = tid & 63;
    if (lane == 0) { sh[wid] = hits; sh[4 + wid] = msum; }
    __syncthreads();
    if (tid == 0) {
        int H = sh[0] + sh[1] + sh[2] + sh[3];
        int M = sh[4] + sh[5] + sh[6] + sh[7];
        out[0] = (float)H / (float)M;
    }
}

// ================= round-1 verified fp32 fallback (if ws too small) =================
#define BM 128
#define BN 128
#define BK 16
#define TM 8
#define TN 8

__global__ __launch_bounds__(64) void w2_kernel_fb(const float* __restrict__ W,
                                                   float* __restrict__ w2) {
    int v = blockIdx.x;
    const float4* w4 = (const float4*)(W + (size_t)v * DIM);
    int lane = threadIdx.x;
    float4 a = w4[lane];
    float4 b = w4[lane + 64];
    float s = a.x*a.x + a.y*a.y + a.z*a.z + a.w*a.w
            + b.x*b.x + b.y*b.y + b.z*b.z + b.w*b.w;
    #pragma unroll
    for (int off = 32; off > 0; off >>= 1) s += __shfl_down(s, off, 64);
    if (lane == 0) w2[v] = s;
}

__global__ __launch_bounds__(256) void count_kernel_fb(
        const float* __restrict__ X, const float* __restrict__ W,
        const float* __restrict__ w2, const float* __restrict__ st,
        const int* __restrict__ target, int* __restrict__ count) {
    __shared__ float Xs[BK][BM];
    __shared__ float Ws[BK][BN];
    __shared__ float st_s[BM];
    __shared__ int   t_s[BM];
    __shared__ float w2_s[BN];
    const int tid  = threadIdx.x;
    const int row0 = blockIdx.y * BM;
    const int col0 = blockIdx.x * BN;
    if (tid < 128) { st_s[tid] = st[row0 + tid]; t_s[tid] = target[row0 + tid]; }
    else { int cc = tid - 128; int v = col0 + cc; if (v >= VOCAB) v = VOCAB - 1; w2_s[cc] = w2[v]; }
    float acc[TM][TN] = {};
    const int tx = tid & 15;
    const int ty = tid >> 4;
    for (int k0 = 0; k0 < DIM; k0 += BK) {
        #pragma unroll
        for (int j = 0; j < 2; j++) {
            int idx = tid + 256 * j;
            int r   = idx >> 2;
            int kq  = idx & 3;
            float4 xv = *(const float4*)(X + (size_t)(row0 + r) * DIM + k0 + kq * 4);
            Xs[kq*4+0][r] = xv.x; Xs[kq*4+1][r] = xv.y;
            Xs[kq*4+2][r] = xv.z; Xs[kq*4+3][r] = xv.w;
            int v = col0 + r; if (v >= VOCAB) v = VOCAB - 1;
            float4 wv = *(const float4*)(W + (size_t)v * DIM + k0 + kq * 4);
            Ws[kq*4+0][r] = wv.x; Ws[kq*4+1][r] = wv.y;
            Ws[kq*4+2][r] = wv.z; Ws[kq*4+3][r] = wv.w;
        }
        __syncthreads();
        #pragma unroll
        for (int kk = 0; kk < BK; kk++) {
            float a[TM], b[TN];
            #pragma unroll
            for (int i = 0; i < TM; i++) a[i] = Xs[kk][ty * TM + i];
            #pragma unroll
            for (int j = 0; j < TN; j++) b[j] = Ws[kk][tx * TN + j];
            #pragma unroll
            for (int i = 0; i < TM; i++)
                #pragma unroll
                for (int j = 0; j < TN; j++)
                    acc[i][j] += a[i] * b[j];
        }
        __syncthreads();
    }
    int cnt[TM];
    #pragma unroll
    for (int i = 0; i < TM; i++) {
        cnt[i] = 0;
        float stv = st_s[ty * TM + i];
        int   t   = t_s[ty * TM + i];
        #pragma unroll
        for (int j = 0; j < TN; j++) {
            int v = col0 + tx * TN + j;
            float s = w2_s[tx * TN + j] - 2.0f * acc[i][j];
            if (v < VOCAB && v != t && (s < stv || (s == stv && v < t))) cnt[i]++;
        }
    }
    __syncthreads();
    int* scnt = (int*)Xs;
    #pragma unroll
    for (int i = 0; i < TM; i++) scnt[(ty * TM + i) * 16 + tx] = cnt[i];
    __syncthreads();
    if (tid < BM) {
        int s = 0;
        #pragma unroll
        for (int j = 0; j < 16; j++) s += scnt[tid * 16 + j];
        atomicAdd(&count[row0 + tid], s);
    }
}

__global__ __launch_bounds__(256) void finalize_fb(const int* __restrict__ count,
                                                   const int* __restrict__ mask,
                                                   float* __restrict__ out) {
    int tid = threadIdx.x;
    int hits = 0, msum = 0;
    for (int n = tid; n < N_ROWS; n += 256) {
        int m = mask[n];
        msum += m;
        if (m && count[n] < TOPK) hits++;
    }
    #pragma unroll
    for (int off = 32; off > 0; off >>= 1) {
        hits += __shfl_down(hits, off, 64);
        msum += __shfl_down(msum, off, 64);
    }
    __shared__ int sh[8];
    int wid = tid >> 6, lane = tid & 63;
    if (lane == 0) { sh[wid] = hits; sh[4 + wid] = msum; }
    __syncthreads();
    if (tid == 0) {
        int H = sh[0] + sh[1] + sh[2] + sh[3];
        int M = sh[4] + sh[5] + sh[6] + sh[7];
        out[0] = (float)H / (float)M;
    }
}

// ================= launch =================
extern "C" void kernel_launch(void* const* d_in, const int* in_sizes, int n_in,
                              void* d_out, int out_size, void* d_ws, size_t ws_size,
                              hipStream_t stream) {
    const float* X      = (const float*)d_in[0];
    const int*   target = (const int*)d_in[1];
    const int*   mask   = (const int*)d_in[2];
    const float* W      = (const float*)d_in[3];
    float* out = (float*)d_out;
    char* ws = (char*)d_ws;

    const size_t oXq   = 0;
    const size_t oWq   = oXq  + (size_t)N_ROWS * DIM;       //  2,097,152
    const size_t osx   = oWq  + (size_t)VPAD  * DIM;        // 27,721,728
    const size_t osw   = osx  + (size_t)N_ROWS * 4;
    const size_t ow2   = osw  + (size_t)VPAD * 4;
    const size_t ost   = ow2  + (size_t)VPAD * 4;
    const size_t ocd   = ost  + (size_t)N_ROWS * 4;
    const size_t ocu   = ocd  + (size_t)N_ROWS * 4;
    const size_t oce   = ocu  + (size_t)N_ROWS * 4;
    const size_t ohit  = oce  + (size_t)N_ROWS * 4;
    const size_t oamb  = ohit + (size_t)N_ROWS * 4;
    const size_t oambc = oamb + (size_t)N_ROWS * 4;
    const size_t need  = oambc + 16;

    if (ws_size >= need) {
        signed char* Xq = (signed char*)(ws + oXq);
        signed char* Wq = (signed char*)(ws + oWq);
        float* sx = (float*)(ws + osx);
        float* sw = (float*)(ws + osw);
        float* w2 = (float*)(ws + ow2);
        float* st = (float*)(ws + ost);
        int* cnt_def = (int*)(ws + ocd);
        int* cnt_unc = (int*)(ws + ocu);
        int* count_exact = (int*)(ws + oce);
        int* hit = (int*)(ws + ohit);
        int* amb_rows = (int*)(ws + oamb);
        int* amb_count = (int*)(ws + oambc);

        hipMemsetAsync(ws + ocd, 0, oambc + 16 - ocd, stream);  // cnt_def..amb_count
        quantize_x<<<N_ROWS / 4, 256, 0, stream>>>(X, Xq, sx);
        quantize_w<<<VPAD / 4, 256, 0, stream>>>(W, Wq, sw, w2);
        st_kernel<<<N_ROWS, 64, 0, stream>>>(X, W, target, st);
        count_mfma_i8<<<dim3(N_ROWS / 128, VPAD / 128), 256, 0, stream>>>(
            Xq, Wq, sx, sw, w2, st, target, cnt_def, cnt_unc);
        resolve_kernel<<<16, 256, 0, stream>>>(cnt_def, cnt_unc, hit, amb_rows, amb_count);
        exact_kernel<<<2048, 256, 0, stream>>>(X, W, w2, st, target, amb_rows, amb_count, count_exact);
        finalize2<<<1, 256, 0, stream>>>(hit, count_exact, mask, out);
    } else {
        float* w2 = (float*)ws;                       // 50000 f -> 200704 B padded
        float* st = (float*)(ws + 200704);
        int* countp = (int*)(ws + 200704 + 16384);
        hipMemsetAsync(countp, 0, N_ROWS * sizeof(int), stream);
        w2_kernel_fb<<<VOCAB, 64, 0, stream>>>(W, w2);
        st_kernel<<<N_ROWS, 64, 0, stream>>>(X, W, target, st);
        dim3 grid((VOCAB + BN - 1) / BN, N_ROWS / BM);
        count_kernel_fb<<<grid, 256, 0, stream>>>(X, W, w2, st, target, countp);
        finalize_fb<<<1, 256, 0, stream>>>(countp, mask, out);
    }
}